// Round 3
// baseline (200.852 us; speedup 1.0000x reference)
//
#include <hip/hip_runtime.h>
#include <string.h>

// Problem constants (from reference setup_inputs)
#define Hh   256
#define SIXH 1536
#define Bb_  32
#define Ll_  512
#define BL_  16384   // B*L
#define Mm_  1024
#define N1_  1024    // 4H
#define K1_  1536    // 6H
#define K2_  1024
#define N2_  256

typedef __attribute__((ext_vector_type(8))) short bf16x8;
typedef __attribute__((ext_vector_type(4))) float f32x4;

__device__ inline float bf2f(unsigned short u){ unsigned x=(unsigned)u<<16; float f; memcpy(&f,&x,4); return f; }
__device__ inline unsigned short f2bf(float f){ unsigned x; memcpy(&x,&f,4); x = x + 0x7FFFu + ((x>>16)&1u); return (unsigned short)(x>>16); }

#define GL16(gp, lp) __builtin_amdgcn_global_load_lds( \
    (const __attribute__((address_space(1))) void*)(gp), \
    (__attribute__((address_space(3))) void*)(lp), 16, 0, 0)

// ---------------------------------------------------------------------------
// Mask dtype detection: flag 0 = int32, 1 = byte(bool), 2 = float32.
__global__ void detect_mask_kernel(const unsigned int* __restrict__ m, int* __restrict__ flag){
  int t = threadIdx.x;
  bool gt1=false, isf=false;
  for (int i=t;i<4096;i+=256){ unsigned v=m[i]; if(v>1u) gt1=true; if(v==0x3F800000u) isf=true; }
  unsigned long long bg = __ballot(gt1), bf = __ballot(isf);
  __shared__ unsigned long long s1[4], s2[4];
  int w = t>>6;
  if ((t&63)==0){ s1[w]=bg; s2[w]=bf; }
  __syncthreads();
  if (t==0){
    bool g = (s1[0]|s1[1]|s1[2]|s1[3])!=0ull;
    bool f = (s2[0]|s2[1]|s2[2]|s2[3])!=0ull;
    *flag = g ? (f?2:1) : 0;
  }
}

// ---------------------------------------------------------------------------
// Tiled transpose + fp32->bf16 convert: W [K][N] f32  ->  Wt [N][K] bf16.
__global__ __launch_bounds__(256) void transpose_conv_kernel(
  const float* __restrict__ W, unsigned short* __restrict__ Wt, int K, int N)
{
  __shared__ float t[32][33];
  int ntx = N >> 5;
  int bx = blockIdx.x % ntx;
  int by = blockIdx.x / ntx;
  int tx = threadIdx.x & 31, ty = threadIdx.x >> 5;
  #pragma unroll
  for (int i=0;i<32;i+=8)
    t[ty+i][tx] = W[(size_t)(by*32+ty+i)*N + bx*32+tx];
  __syncthreads();
  #pragma unroll
  for (int i=0;i<32;i+=8)
    Wt[(size_t)(bx*32+ty+i)*K + by*32+tx] = f2bf(t[tx][ty+i]);
}

// ---------------------------------------------------------------------------
// Gather 6 embedding segments + LayerNorm(1536) -> xn bf16 [16384][1536]
__global__ __launch_bounds__(256) void gather_ln_kernel(
  const int* __restrict__ tok, const int* __restrict__ post,
  const int* __restrict__ auth, const int* __restrict__ act,
  const int* __restrict__ tg,  const int* __restrict__ gidp,
  const float* __restrict__ token_emb, const float* __restrict__ time_emb,
  const float* __restrict__ group_emb,
  const float* __restrict__ ln_g, const float* __restrict__ ln_b,
  unsigned short* __restrict__ xn)
{
  int row = blockIdx.x;
  int t   = threadIdx.x;
  int i0 = tok[row], i1 = post[row], i2 = auth[row], i3 = act[row];
  int i4 = tg[row]; i4 = (i4 < 0) ? 0 : (i4 > 64 ? 64 : i4);
  int i5 = gidp[row];
  float v[6];
  v[0] = token_emb[(size_t)i0*Hh + t];
  v[1] = token_emb[(size_t)i1*Hh + t];
  v[2] = token_emb[(size_t)i2*Hh + t];
  v[3] = token_emb[(size_t)i3*Hh + t];
  v[4] = time_emb[i4*Hh + t];
  v[5] = group_emb[i5*Hh + t];
  float s=0.f, s2=0.f;
  #pragma unroll
  for (int i=0;i<6;i++){ s+=v[i]; s2+=v[i]*v[i]; }
  #pragma unroll
  for (int off=32; off; off>>=1){ s += __shfl_xor(s,off); s2 += __shfl_xor(s2,off); }
  __shared__ float rs[4], rs2[4];
  int w=t>>6;
  if ((t&63)==0){ rs[w]=s; rs2[w]=s2; }
  __syncthreads();
  s  = rs[0]+rs[1]+rs[2]+rs[3];
  s2 = rs2[0]+rs2[1]+rs2[2]+rs2[3];
  float mu   = s * (1.0f/1536.0f);
  float var  = s2 * (1.0f/1536.0f) - mu*mu;
  float rstd = rsqrtf(var + 1e-5f);
  unsigned short* xr = xn + (size_t)row*SIXH;
  #pragma unroll
  for (int i=0;i<6;i++){
    int j = i*Hh + t;
    float y = (v[i]-mu)*rstd*ln_g[j] + ln_b[j];
    xr[j] = f2bf(y);
  }
}

// ---------------------------------------------------------------------------
// GEMM1: 256x256 tile, 8 waves (2Mx4N), BK=64, 4 phases per K-tile.
// m201-style schedule: per phase {ds-read next-needed half-subtile || stage
// one half-tile via global_load_lds -> MFMA quadrant -> lgkmcnt(0) -> barrier}.
// Counted vmcnt(8) twice per K-tile (never 0 in steady state).
// Register diet vs R2: 8 precomputed per-lane staging pointers bumped by
// +128 elem per 2-tile iteration; in-loop stage offsets are constant imms.
// LDS: A slot s at s*16384 elem (half h at +h*8192); B at +32768. 128 KiB.
// Swizzle: 16B granule g of row r stored at g ^ (r&7) (involution, both sides).
// Quadrant row map: row = wr*64 + mh*128 + q*16; col = wc*32 + nh*128 + nn*16.
// A [M][K] bf16, Bt [N][K] bf16, C = silu(A@Bt^T + bias) as bf16 [M][N].
__global__ __launch_bounds__(512, 2) void gemm1_pipe2_kernel(
  const unsigned short* __restrict__ A, const unsigned short* __restrict__ Bt,
  const float* __restrict__ bias, unsigned short* __restrict__ C,
  int M, int N, int K)
{
  __shared__ unsigned short lds[65536];

  int nbx = N >> 8;
  int bid = blockIdx.x;
  if ((gridDim.x & 7) == 0){                // XCD swizzle (bijective, nwg%8==0)
    int chunk = gridDim.x >> 3;
    bid = (bid & 7)*chunk + (bid >> 3);
  }
  int bx = bid % nbx, by = bid / nbx;
  int brow = by*256, bcol = bx*256;

  int tid = threadIdx.x, lane = tid & 63, wid = tid >> 6;
  int wr = wid >> 2, wc = wid & 3;          // 2 x 4 wave grid

  // ---- staging lane geometry (pre-swizzled global, linear LDS dest) ----
  int sR  = lane >> 3;                      // row within 8-row inst block
  int sSw = ((lane & 7) ^ sR) << 3;         // swizzled granule (elements)

  // 8 per-lane global pointers at K-tile 0; bumped +128 per 2-tile iteration.
  const unsigned short* pA0a = A  + (size_t)(brow +       wid*16 + sR)*K + sSw;
  const unsigned short* pA0b = pA0a + (size_t)8*K;
  const unsigned short* pA1a = A  + (size_t)(brow + 128 + wid*16 + sR)*K + sSw;
  const unsigned short* pA1b = pA1a + (size_t)8*K;
  const unsigned short* pB0a = Bt + (size_t)(bcol +       wid*16 + sR)*K + sSw;
  const unsigned short* pB0b = pB0a + (size_t)8*K;
  const unsigned short* pB1a = Bt + (size_t)(bcol + 128 + wid*16 + sR)*K + sSw;
  const unsigned short* pB1b = pB1a + (size_t)8*K;
  unsigned short* ldsW = lds + wid*1024;    // wave-uniform LDS base

  // ---- per-lane fragment read bases (swizzled), in elements ----
  int fr = lane & 15, kb = lane >> 4;
  int g0  = (kb ^ (fr & 3)) | (fr & 4);     // granule for kc=0; kc=1 -> ^32 elems
  int aB0 = (wr*64 + fr)*64 + g0*8;  int aB1 = aB0 ^ 32;
  int bB0 = (wc*32 + fr)*64 + g0*8;  int bB1 = bB0 ^ 32;

  f32x4 acc[8][4];
  #pragma unroll
  for (int m=0;m<8;m++)
    #pragma unroll
    for (int n=0;n<4;n++) acc[m][n] = (f32x4){0.f,0.f,0.f,0.f};

  bf16x8 a0F[8], a1F[8], bP[4], bQ[4];

#define RD_A(buf, mh, S) do{ \
    const unsigned short* L_ = lds + (S)*16384 + (mh)*8192; \
    _Pragma("unroll") for (int q=0;q<4;q++){ \
      buf[2*q]   = *(const bf16x8*)(L_ + aB0 + q*1024); \
      buf[2*q+1] = *(const bf16x8*)(L_ + aB1 + q*1024); } }while(0)

#define RD_B(buf, nh, S) do{ \
    const unsigned short* L_ = lds + 32768 + (S)*16384 + (nh)*8192; \
    _Pragma("unroll") for (int nn=0;nn<2;nn++){ \
      buf[2*nn]   = *(const bf16x8*)(L_ + bB0 + nn*1024); \
      buf[2*nn+1] = *(const bf16x8*)(L_ + bB1 + nn*1024); } }while(0)

  // Stage one half-tile: 2 GL16 from pointer pair (pa, pb) at constant OFF.
#define STG(pa, pb, dofs, OFF) do{ \
    GL16((pa) + (OFF), ldsW + (dofs)); \
    GL16((pb) + (OFF), ldsW + (dofs) + 512); }while(0)

#define MM(mh, nh, AF, BF) do{ \
    __builtin_amdgcn_s_setprio(1); \
    _Pragma("unroll") for (int kc=0;kc<2;kc++) \
     _Pragma("unroll") for (int q=0;q<4;q++) \
      _Pragma("unroll") for (int nn=0;nn<2;nn++) \
        acc[(mh)*4+q][(nh)*2+nn] = __builtin_amdgcn_mfma_f32_16x16x32_bf16( \
            AF[2*q+kc], BF[2*nn+kc], acc[(mh)*4+q][(nh)*2+nn], 0, 0, 0); \
    __builtin_amdgcn_s_setprio(0); }while(0)

#define SEAL asm volatile("s_waitcnt lgkmcnt(0)" ::: "memory")
#define BAR  __builtin_amdgcn_s_barrier()
#define VM8  asm volatile("s_waitcnt vmcnt(8)" ::: "memory")
#define VM4  asm volatile("s_waitcnt vmcnt(4)" ::: "memory")
#define VM0  asm volatile("s_waitcnt vmcnt(0)" ::: "memory")
#define VNOP do{}while(0)

  // TILE: reads one phase ahead; stages (tile T+2) into just-dead regions of
  // slot S. BP holds B0(T); BQ gets B1(T) at ph1, then B0(T+1) at ph4.
#define TILE(S, BP, BQ, OFF, DOSTG, RDN, V2, V4) do{ \
    /* ph1: MFMA(0,0); stage A-h0 */ \
    RD_B(BQ, 1, S); \
    if (DOSTG) STG(pA0a, pA0b, (S)*16384, OFF); \
    MM(0,0, a0F, BP); \
    SEAL; BAR; \
    /* ph2: MFMA(0,1); stage B-h0 */ \
    RD_A(a1F, 1, S); \
    if (DOSTG) STG(pB0a, pB0b, 32768 + (S)*16384, OFF); \
    MM(0,1, a0F, BQ); \
    SEAL; V2; BAR; \
    /* ph3: MFMA(1,1); stage A-h1 */ \
    if (RDN) RD_A(a0F, 0, (S)^1); \
    if (DOSTG) STG(pA1a, pA1b, (S)*16384 + 8192, OFF); \
    MM(1,1, a1F, BQ); \
    SEAL; BAR; \
    /* ph4: MFMA(1,0); stage B-h1 */ \
    if (RDN) RD_B(BQ, 0, (S)^1); \
    if (DOSTG) STG(pB1a, pB1b, 32768 + (S)*16384 + 8192, OFF); \
    MM(1,0, a1F, BP); \
    SEAL; V4; BAR; \
  }while(0)

  int nk = K >> 6;                          // 24 K-tiles
  // ---- prologue: stage tiles 0 (slot0, off 0) and 1 (slot1, off 64) ----
  STG(pA0a, pA0b, 0,           0);  STG(pB0a, pB0b, 32768,        0);
  STG(pA1a, pA1b, 8192,        0);  STG(pB1a, pB1b, 32768+8192,   0);
  STG(pA0a, pA0b, 16384,       64); STG(pB0a, pB0b, 32768+16384,  64);
  STG(pA1a, pA1b, 16384+8192,  64); STG(pB1a, pB1b, 32768+16384+8192, 64);
  VM8; BAR;
  RD_A(a0F, 0, 0); RD_B(bP, 0, 0);          // A0(0), B0(0)
  SEAL; BAR;

  for (int tt = 0; tt < (nk-2)/2; ++tt){
    TILE(0, bP, bQ, 128, 1, 1, VM8, VM8);
    TILE(1, bQ, bP, 192, 1, 1, VM8, VM8);
    pA0a += 128; pA0b += 128; pA1a += 128; pA1b += 128;
    pB0a += 128; pB0b += 128; pB1a += 128; pB1b += 128;
  }
  TILE(0, bP, bQ, 0, 0, 1, VM4, VM0);
  TILE(1, bQ, bP, 0, 0, 0, VNOP, VNOP);

#undef TILE
#undef RD_A
#undef RD_B
#undef STG
#undef MM

  // ---- epilogue: C/D layout col=lane&15, row=(lane>>4)*4+j ----
  int colb = bcol + wc*32 + fr;
  float bv[4];
  #pragma unroll
  for (int n=0;n<4;n++) bv[n] = bias[colb + (n>>1)*128 + (n&1)*16];
  int r0 = brow + wr*64 + (lane>>4)*4;
  #pragma unroll
  for (int m=0;m<8;m++){
    #pragma unroll
    for (int j=0;j<4;j++){
      int r = r0 + (m>>2)*128 + (m&3)*16 + j;
      #pragma unroll
      for (int n=0;n<4;n++){
        int c = colb + (n>>1)*128 + (n&1)*16;
        float x = acc[m][n][j] + bv[n];
        x = x / (1.0f + expf(-x));
        C[(size_t)r*N + c] = f2bf(x);
      }
    }
  }
}

// ---------------------------------------------------------------------------
// bf16 MFMA GEMM (m97 structure, 128x128): used for GEMM2.
template<bool SILU, bool OUT_BF16>
__global__ __launch_bounds__(256) void gemm_mfma_kernel(
  const unsigned short* __restrict__ A, const unsigned short* __restrict__ Bt,
  const float* __restrict__ bias, void* __restrict__ C,
  int M, int N, int K)
{
  __shared__ unsigned short As[128*32];
  __shared__ unsigned short Bs[128*32];
  int nbx = N >> 7;
  int bx = blockIdx.x % nbx;
  int by = blockIdx.x / nbx;
  int tid  = threadIdx.x;
  int lane = tid & 63;
  int wid  = tid >> 6;
  int wr = wid >> 1, wc = wid & 1;
  const int brow = by*128, bcol = bx*128;

  int g_r = lane >> 2;
  int g_k = (lane & 3) * 8;
  const unsigned short* Ag0 = A  + (size_t)(brow + wid*32 + g_r)*K + g_k;
  const unsigned short* Ag1 = Ag0 + (size_t)16*K;
  const unsigned short* Bg0 = Bt + (size_t)(bcol + wid*32 + g_r)*K + g_k;
  const unsigned short* Bg1 = Bg0 + (size_t)16*K;
  unsigned short* lA0 = &As[(wid*32 +  0)*32];
  unsigned short* lA1 = &As[(wid*32 + 16)*32];
  unsigned short* lB0 = &Bs[(wid*32 +  0)*32];
  unsigned short* lB1 = &Bs[(wid*32 + 16)*32];

  f32x4 acc[4][4];
  #pragma unroll
  for (int i=0;i<4;i++)
    #pragma unroll
    for (int j=0;j<4;j++) acc[i][j] = (f32x4){0.f,0.f,0.f,0.f};

  int fr = lane & 15;
  int fk = (lane >> 4) * 8;

  for (int kt = 0; kt < K; kt += 32){
    GL16(Ag0 + kt, lA0);
    GL16(Ag1 + kt, lA1);
    GL16(Bg0 + kt, lB0);
    GL16(Bg1 + kt, lB1);
    __syncthreads();
    bf16x8 af[4], bfr[4];
    #pragma unroll
    for (int i=0;i<4;i++){
      af[i]  = *(const bf16x8*)&As[(wr*64 + i*16 + fr)*32 + fk];
      bfr[i] = *(const bf16x8*)&Bs[(wc*64 + i*16 + fr)*32 + fk];
    }
    #pragma unroll
    for (int mi=0;mi<4;mi++)
      #pragma unroll
      for (int ni=0;ni<4;ni++)
        acc[mi][ni] = __builtin_amdgcn_mfma_f32_16x16x32_bf16(af[mi], bfr[ni], acc[mi][ni], 0, 0, 0);
    __syncthreads();
  }

  int col0 = bcol + wc*64 + (lane & 15);
  int row0 = brow + wr*64 + (lane >> 4)*4;
  #pragma unroll
  for (int mi=0;mi<4;mi++){
    #pragma unroll
    for (int j=0;j<4;j++){
      int r = row0 + mi*16 + j;
      #pragma unroll
      for (int ni=0;ni<4;ni++){
        int c = col0 + ni*16;
        float x = acc[mi][ni][j] + bias[c];
        if (SILU) x = x / (1.0f + expf(-x));
        if (OUT_BF16) ((unsigned short*)C)[(size_t)r*N + c] = f2bf(x);
        else          ((float*)C)[(size_t)r*N + c] = x;
      }
    }
  }
}

// ---------------------------------------------------------------------------
// Parallel merge metadata: one block of 512 threads per batch (thread = position).
__global__ __launch_bounds__(512) void merge_meta_kernel(
  const void* __restrict__ maskp, const int* __restrict__ gid,
  const int* __restrict__ flag,
  int* __restrict__ src, int* __restrict__ count)
{
  int b = blockIdx.x;
  int i = threadIdx.x;
  int lane = i & 63, w = i >> 6;
  __shared__ int sg[Ll_];
  __shared__ int fv[8];
  __shared__ int wt[8];
  int f = *flag;
  int mv;
  if (f==0)      mv = ((const int*)maskp)[b*Ll_+i];
  else if (f==1) mv = ((const unsigned char*)maskp)[b*Ll_+i];
  else           mv = (((const float*)maskp)[b*Ll_+i] != 0.0f);
  bool m = (mv != 0);
  int g = gid[b*Ll_+i];
  sg[i] = g;
  unsigned long long W = __ballot(m);
  if (lane==0) fv[w] = W ? (w*64 + __builtin_ctzll(W)) : -1;
  __syncthreads();
  unsigned long long rem = (lane==63) ? 0ull : (W >> (lane+1));
  int nxtpos = -1;
  if (rem) nxtpos = w*64 + lane + 1 + __builtin_ctzll(rem);
  else {
    #pragma unroll
    for (int k=0;k<8;k++)
      if (nxtpos < 0 && k > w && fv[k] >= 0) nxtpos = fv[k];
  }
  int nxt = (nxtpos >= 0) ? sg[nxtpos] : -1;
  bool sep = m && (nxt >= 0) && (nxt != g);
  int ci = (m?1:0) + (sep?1:0);
  int v = ci;
  #pragma unroll
  for (int off=1; off<64; off<<=1){
    int u = __shfl_up(v, off);
    if (lane >= off) v += u;
  }
  if (lane==63) wt[w] = v;
  __syncthreads();
  int woff = 0;
  #pragma unroll
  for (int k=0;k<8;k++) if (k < w) woff += wt[k];
  int e = woff + v - ci;
  int* sb = src + b*Mm_;
  if (m){
    sb[e] = 2*i;
    if (sep) sb[e+1] = 2*i+1;
  }
  if (i==0){
    int tot=0;
    #pragma unroll
    for (int k=0;k<8;k++) tot += wt[k];
    count[b] = tot;
  }
}

// ---------------------------------------------------------------------------
// Final output: right-aligned pieces + pos_emb, zeros elsewhere, plus mask plane.
__global__ __launch_bounds__(256) void output_kernel(
  const float* __restrict__ ev, const float* __restrict__ pos_emb,
  const float* __restrict__ sep_token,
  const int* __restrict__ src, const int* __restrict__ count,
  float* __restrict__ out)
{
  int tid  = threadIdx.x;
  int tpos = blockIdx.x*4 + (tid>>6);
  int lane = tid & 63;
  int b = tpos >> 10;
  int t = tpos & 1023;
  int cnt = count[b];
  int start = Mm_ - cnt;
  float4 val = make_float4(0.f,0.f,0.f,0.f);
  float maskv = 0.f;
  if (t >= start){
    maskv = 1.f;
    int slot = src[b*Mm_ + (t - start)];
    const float* sv = (slot & 1) ? sep_token
                                 : ev + (size_t)(b*Ll_ + (slot>>1))*Hh;
    float4 x = *(const float4*)(sv + lane*4);
    float4 p = *(const float4*)(pos_emb + (size_t)t*Hh + lane*4);
    val = make_float4(x.x+p.x, x.y+p.y, x.z+p.z, x.w+p.w);
  }
  *(float4*)(out + (size_t)tpos*Hh + lane*4) = val;
  if (lane==0) out[(size_t)Bb_*Mm_*Hh + tpos] = maskv;
}

// ---------------------------------------------------------------------------
extern "C" void kernel_launch(void* const* d_in, const int* in_sizes, int n_in,
                              void* d_out, int out_size, void* d_ws, size_t ws_size,
                              hipStream_t stream) {
  const int* tok    = (const int*)d_in[0];
  const int* post   = (const int*)d_in[1];
  const int* auth   = (const int*)d_in[2];
  const int* act    = (const int*)d_in[3];
  const int* tg     = (const int*)d_in[4];
  const int* gid    = (const int*)d_in[5];
  const void* maskp =             d_in[6];
  const float* token_emb = (const float*)d_in[7];
  const float* time_emb  = (const float*)d_in[8];
  const float* group_emb = (const float*)d_in[9];
  const float* pos_emb   = (const float*)d_in[10];
  const float* sep_token = (const float*)d_in[11];
  const float* ln_g = (const float*)d_in[12];
  const float* ln_b = (const float*)d_in[13];
  const float* W1   = (const float*)d_in[14];
  const float* b1   = (const float*)d_in[15];
  const float* W2   = (const float*)d_in[16];
  const float* b2   = (const float*)d_in[17];

  char* ws = (char*)d_ws;
  size_t off = 0;
  int* flag = (int*)ws;                                  off += 256;
  unsigned short* xn  = (unsigned short*)(ws + off);     off += (size_t)BL_*SIXH*2;
  unsigned short* h1  = (unsigned short*)(ws + off);     off += (size_t)BL_*N1_*2;
  float*          ev  = (float*)(ws + off);              off += (size_t)BL_*N2_*4;
  unsigned short* w1t = (unsigned short*)(ws + off);     off += (size_t)K1_*N1_*2;
  unsigned short* w2t = (unsigned short*)(ws + off);     off += (size_t)K2_*N2_*2;
  int*            src = (int*)(ws + off);                off += (size_t)Bb_*Mm_*4;
  int*            cnt = (int*)(ws + off);                off += 256;

  detect_mask_kernel<<<1,256,0,stream>>>((const unsigned int*)maskp, flag);
  transpose_conv_kernel<<<(K1_/32)*(N1_/32),256,0,stream>>>(W1, w1t, K1_, N1_);
  transpose_conv_kernel<<<(K2_/32)*(N2_/32),256,0,stream>>>(W2, w2t, K2_, N2_);
  gather_ln_kernel<<<BL_,256,0,stream>>>(tok,post,auth,act,tg,gid,
                                         token_emb,time_emb,group_emb,
                                         ln_g,ln_b,xn);
  gemm1_pipe2_kernel<<<(BL_/256)*(N1_/256),512,0,stream>>>(
      xn, w1t, b1, h1, BL_, N1_, K1_);
  gemm_mfma_kernel<false,false><<<(BL_/128)*(N2_/128),256,0,stream>>>(
      h1, w2t, b2, (void*)ev, BL_, N2_, K2_);
  merge_meta_kernel<<<Bb_,512,0,stream>>>(maskp, gid, flag, src, cnt);
  output_kernel<<<(Bb_*Mm_)/4,256,0,stream>>>(ev, pos_emb, sep_token, src, cnt, (float*)d_out);
}

// Round 4
// 136.937 us; speedup vs baseline: 1.4667x; 1.4667x over previous
//
#include <hip/hip_runtime.h>
#include <string.h>

// Problem constants (from reference setup_inputs)
#define Hh   256
#define SIXH 1536
#define Bb_  32
#define Ll_  512
#define BL_  16384   // B*L
#define Mm_  1024
#define N1_  1024    // 4H
#define K1_  1536    // 6H
#define K2_  1024
#define N2_  256

typedef __attribute__((ext_vector_type(8))) short bf16x8;
typedef __attribute__((ext_vector_type(4))) float f32x4;

__device__ inline float bf2f(unsigned short u){ unsigned x=(unsigned)u<<16; float f; memcpy(&f,&x,4); return f; }
__device__ inline unsigned short f2bf(float f){ unsigned x; memcpy(&x,&f,4); x = x + 0x7FFFu + ((x>>16)&1u); return (unsigned short)(x>>16); }

#define GL16(gp, lp) __builtin_amdgcn_global_load_lds( \
    (const __attribute__((address_space(1))) void*)(gp), \
    (__attribute__((address_space(3))) void*)(lp), 16, 0, 0)

// ---------------------------------------------------------------------------
// Mask dtype detection: flag 0 = int32, 1 = byte(bool), 2 = float32.
__global__ void detect_mask_kernel(const unsigned int* __restrict__ m, int* __restrict__ flag){
  int t = threadIdx.x;
  bool gt1=false, isf=false;
  for (int i=t;i<4096;i+=256){ unsigned v=m[i]; if(v>1u) gt1=true; if(v==0x3F800000u) isf=true; }
  unsigned long long bg = __ballot(gt1), bf = __ballot(isf);
  __shared__ unsigned long long s1[4], s2[4];
  int w = t>>6;
  if ((t&63)==0){ s1[w]=bg; s2[w]=bf; }
  __syncthreads();
  if (t==0){
    bool g = (s1[0]|s1[1]|s1[2]|s1[3])!=0ull;
    bool f = (s2[0]|s2[1]|s2[2]|s2[3])!=0ull;
    *flag = g ? (f?2:1) : 0;
  }
}

// ---------------------------------------------------------------------------
// Tiled transpose + fp32->bf16 convert: W [K][N] f32  ->  Wt [N][K] bf16.
__global__ __launch_bounds__(256) void transpose_conv_kernel(
  const float* __restrict__ W, unsigned short* __restrict__ Wt, int K, int N)
{
  __shared__ float t[32][33];
  int ntx = N >> 5;
  int bx = blockIdx.x % ntx;
  int by = blockIdx.x / ntx;
  int tx = threadIdx.x & 31, ty = threadIdx.x >> 5;
  #pragma unroll
  for (int i=0;i<32;i+=8)
    t[ty+i][tx] = W[(size_t)(by*32+ty+i)*N + bx*32+tx];
  __syncthreads();
  #pragma unroll
  for (int i=0;i<32;i+=8)
    Wt[(size_t)(bx*32+ty+i)*K + by*32+tx] = f2bf(t[tx][ty+i]);
}

// ---------------------------------------------------------------------------
// Gather 6 embedding segments + LayerNorm(1536) -> xn bf16 [16384][1536]
__global__ __launch_bounds__(256) void gather_ln_kernel(
  const int* __restrict__ tok, const int* __restrict__ post,
  const int* __restrict__ auth, const int* __restrict__ act,
  const int* __restrict__ tg,  const int* __restrict__ gidp,
  const float* __restrict__ token_emb, const float* __restrict__ time_emb,
  const float* __restrict__ group_emb,
  const float* __restrict__ ln_g, const float* __restrict__ ln_b,
  unsigned short* __restrict__ xn)
{
  int row = blockIdx.x;
  int t   = threadIdx.x;
  int i0 = tok[row], i1 = post[row], i2 = auth[row], i3 = act[row];
  int i4 = tg[row]; i4 = (i4 < 0) ? 0 : (i4 > 64 ? 64 : i4);
  int i5 = gidp[row];
  float v[6];
  v[0] = token_emb[(size_t)i0*Hh + t];
  v[1] = token_emb[(size_t)i1*Hh + t];
  v[2] = token_emb[(size_t)i2*Hh + t];
  v[3] = token_emb[(size_t)i3*Hh + t];
  v[4] = time_emb[i4*Hh + t];
  v[5] = group_emb[i5*Hh + t];
  float s=0.f, s2=0.f;
  #pragma unroll
  for (int i=0;i<6;i++){ s+=v[i]; s2+=v[i]*v[i]; }
  #pragma unroll
  for (int off=32; off; off>>=1){ s += __shfl_xor(s,off); s2 += __shfl_xor(s2,off); }
  __shared__ float rs[4], rs2[4];
  int w=t>>6;
  if ((t&63)==0){ rs[w]=s; rs2[w]=s2; }
  __syncthreads();
  s  = rs[0]+rs[1]+rs[2]+rs[3];
  s2 = rs2[0]+rs2[1]+rs2[2]+rs2[3];
  float mu   = s * (1.0f/1536.0f);
  float var  = s2 * (1.0f/1536.0f) - mu*mu;
  float rstd = rsqrtf(var + 1e-5f);
  unsigned short* xr = xn + (size_t)row*SIXH;
  #pragma unroll
  for (int i=0;i<6;i++){
    int j = i*Hh + t;
    float y = (v[i]-mu)*rstd*ln_g[j] + ln_b[j];
    xr[j] = f2bf(y);
  }
}

// ---------------------------------------------------------------------------
// GEMM1: 256x256 tile, 8 waves (2Mx4N), BK=64, 4 phases per K-tile.
// m201-faithful: reads IN-PHASE (frag live-set = 16 bf16x8 = 64 VGPR, no
// read-ahead), per phase {ds-read subtile; stage; barrier; lgkmcnt(0);
// setprio(1) 16xMFMA setprio(0); barrier}. Stage depth = 2 K-tiles: iter T
// stages tile T+2 into just-dead regions of the slot being consumed
// (A0,B0 die after ph1 -> staged ph2; B1 after ph2 -> ph3; A1 after ph3 ->
// ph4). Counted vmcnt(8) ONCE per K-tile at ph4 (8 = own stages this iter),
// guaranteeing tile T+1 complete; vmcnt(0) only in the peeled tail.
// LDS: A slot s at s*16384 elem (half h at +h*8192); B at +32768. 128 KiB.
// Swizzle: 16B granule g of row r stored at g ^ (r&7) (involution, both sides).
// Quadrant row map: row = wr*64 + mh*128 + q*16; col = wc*32 + nh*128 + nn*16.
// A [M][K] bf16, Bt [N][K] bf16, C = silu(A@Bt^T + bias) as bf16 [M][N].
__global__ __launch_bounds__(512, 2) void gemm1_m201_kernel(
  const unsigned short* __restrict__ A, const unsigned short* __restrict__ Bt,
  const float* __restrict__ bias, unsigned short* __restrict__ C,
  int M, int N, int K)
{
  __shared__ unsigned short lds[65536];

  int nbx = N >> 8;
  int bid = blockIdx.x;
  if ((gridDim.x & 7) == 0){                // XCD swizzle (bijective, nwg%8==0)
    int chunk = gridDim.x >> 3;
    bid = (bid & 7)*chunk + (bid >> 3);
  }
  int bx = bid % nbx, by = bid / nbx;
  int brow = by*256, bcol = bx*256;

  int tid = threadIdx.x, lane = tid & 63, wid = tid >> 6;
  int wr = wid >> 2, wc = wid & 3;          // 2 x 4 wave grid

  // ---- staging lane geometry (pre-swizzled global, linear LDS dest) ----
  int sR  = lane >> 3;                      // row within 8-row inst block
  int sSw = ((lane & 7) ^ sR) << 3;         // swizzled granule (elements)

  // 8 per-lane global pointers at K-tile 0; bumped +128 per 2-tile iteration.
  const unsigned short* pA0a = A  + (size_t)(brow +       wid*16 + sR)*K + sSw;
  const unsigned short* pA0b = pA0a + (size_t)8*K;
  const unsigned short* pA1a = A  + (size_t)(brow + 128 + wid*16 + sR)*K + sSw;
  const unsigned short* pA1b = pA1a + (size_t)8*K;
  const unsigned short* pB0a = Bt + (size_t)(bcol +       wid*16 + sR)*K + sSw;
  const unsigned short* pB0b = pB0a + (size_t)8*K;
  const unsigned short* pB1a = Bt + (size_t)(bcol + 128 + wid*16 + sR)*K + sSw;
  const unsigned short* pB1b = pB1a + (size_t)8*K;
  unsigned short* ldsW = lds + wid*1024;    // wave-uniform LDS base

  // ---- per-lane fragment read bases (swizzled), in elements ----
  int fr = lane & 15, kb = lane >> 4;
  int g0  = (kb ^ (fr & 3)) | (fr & 4);     // granule for kc=0; kc=1 -> ^32 elems
  int aB0 = (wr*64 + fr)*64 + g0*8;  int aB1 = aB0 ^ 32;
  int bB0 = (wc*32 + fr)*64 + g0*8;  int bB1 = bB0 ^ 32;

  f32x4 acc[8][4];
  #pragma unroll
  for (int m=0;m<8;m++)
    #pragma unroll
    for (int n=0;n<4;n++) acc[m][n] = (f32x4){0.f,0.f,0.f,0.f};

  bf16x8 aF[8], bP[4], bQ[4];   // in-phase frags: 16 x bf16x8 = 64 VGPR

#define RD_A(buf, mh, S) do{ \
    const unsigned short* L_ = lds + (S)*16384 + (mh)*8192; \
    _Pragma("unroll") for (int q=0;q<4;q++){ \
      buf[2*q]   = *(const bf16x8*)(L_ + aB0 + q*1024); \
      buf[2*q+1] = *(const bf16x8*)(L_ + aB1 + q*1024); } }while(0)

#define RD_B(buf, nh, S) do{ \
    const unsigned short* L_ = lds + 32768 + (S)*16384 + (nh)*8192; \
    _Pragma("unroll") for (int nn=0;nn<2;nn++){ \
      buf[2*nn]   = *(const bf16x8*)(L_ + bB0 + nn*1024); \
      buf[2*nn+1] = *(const bf16x8*)(L_ + bB1 + nn*1024); } }while(0)

  // Stage one half-tile: 2 GL16 from pointer pair (pa, pb) at constant OFF.
#define STG(pa, pb, dofs, OFF) do{ \
    GL16((pa) + (OFF), ldsW + (dofs)); \
    GL16((pb) + (OFF), ldsW + (dofs) + 512); }while(0)

#define MM(mh, nh, BF) do{ \
    __builtin_amdgcn_s_setprio(1); \
    _Pragma("unroll") for (int kc=0;kc<2;kc++) \
     _Pragma("unroll") for (int q=0;q<4;q++) \
      _Pragma("unroll") for (int nn=0;nn<2;nn++) \
        acc[(mh)*4+q][(nh)*2+nn] = __builtin_amdgcn_mfma_f32_16x16x32_bf16( \
            aF[2*q+kc], BF[2*nn+kc], acc[(mh)*4+q][(nh)*2+nn], 0, 0, 0); \
    __builtin_amdgcn_s_setprio(0); }while(0)

#define SEAL asm volatile("s_waitcnt lgkmcnt(0)" ::: "memory")
#define BAR  __builtin_amdgcn_s_barrier()
#define VM8  asm volatile("s_waitcnt vmcnt(8)" ::: "memory")
#define VM0  asm volatile("s_waitcnt vmcnt(0)" ::: "memory")
#define VNOP do{}while(0)

  // One K-tile = 4 phases. Stage targets are just-dead regions of slot S.
#define TILE(S, OFF, DOSTG, V4) do{ \
    /* ph1: read A0+B0(S); MFMA(0,0) */ \
    RD_B(bP, 0, S); \
    RD_A(aF, 0, S); \
    BAR; SEAL; \
    MM(0,0, bP); \
    BAR; \
    /* ph2: read B1(S); stage A0,B0(T+2); MFMA(0,1) */ \
    RD_B(bQ, 1, S); \
    if (DOSTG){ STG(pA0a, pA0b, (S)*16384, OFF); \
                STG(pB0a, pB0b, 32768 + (S)*16384, OFF); } \
    BAR; SEAL; \
    MM(0,1, bQ); \
    BAR; \
    /* ph3: read A1(S); stage B1(T+2); MFMA(1,1) */ \
    RD_A(aF, 1, S); \
    if (DOSTG) STG(pB1a, pB1b, 32768 + (S)*16384 + 8192, OFF); \
    BAR; SEAL; \
    MM(1,1, bQ); \
    BAR; \
    /* ph4: stage A1(T+2); MFMA(1,0); counted drain */ \
    if (DOSTG) STG(pA1a, pA1b, (S)*16384 + 8192, OFF); \
    MM(1,0, bP); \
    V4; BAR; \
  }while(0)

  int nk = K >> 6;                          // 24 K-tiles
  // ---- prologue: stage tiles 0 (slot0, off 0) and 1 (slot1, off 64) ----
  STG(pA0a, pA0b, 0,           0);  STG(pB0a, pB0b, 32768,        0);
  STG(pB1a, pB1b, 32768+8192,  0);  STG(pA1a, pA1b, 8192,         0);
  STG(pA0a, pA0b, 16384,       64); STG(pB0a, pB0b, 32768+16384,  64);
  STG(pB1a, pB1b, 32768+16384+8192, 64); STG(pA1a, pA1b, 16384+8192, 64);
  VM8; BAR;                                 // tile 0 landed (8 = tile 1 in flight)

  for (int tt = 0; tt < (nk-2)/2; ++tt){
    TILE(0, 128, 1, VM8);
    TILE(1, 192, 1, VM8);
    pA0a += 128; pA0b += 128; pA1a += 128; pA1b += 128;
    pB0a += 128; pB0b += 128; pB1a += 128; pB1b += 128;
  }
  TILE(0, 0, 0, VM0);                       // T=nk-2: drain tile nk-1's stages
  TILE(1, 0, 0, VNOP);                      // T=nk-1

#undef TILE
#undef RD_A
#undef RD_B
#undef STG
#undef MM

  // ---- epilogue: C/D layout col=lane&15, row=(lane>>4)*4+j ----
  int colb = bcol + wc*32 + fr;
  float bv[4];
  #pragma unroll
  for (int n=0;n<4;n++) bv[n] = bias[colb + (n>>1)*128 + (n&1)*16];
  int r0 = brow + wr*64 + (lane>>4)*4;
  #pragma unroll
  for (int m=0;m<8;m++){
    #pragma unroll
    for (int j=0;j<4;j++){
      int r = r0 + (m>>2)*128 + (m&3)*16 + j;
      #pragma unroll
      for (int n=0;n<4;n++){
        int c = colb + (n>>1)*128 + (n&1)*16;
        float x = acc[m][n][j] + bv[n];
        x = x / (1.0f + expf(-x));
        C[(size_t)r*N + c] = f2bf(x);
      }
    }
  }
}

// ---------------------------------------------------------------------------
// bf16 MFMA GEMM (m97 structure, 128x128): used for GEMM2.
template<bool SILU, bool OUT_BF16>
__global__ __launch_bounds__(256) void gemm_mfma_kernel(
  const unsigned short* __restrict__ A, const unsigned short* __restrict__ Bt,
  const float* __restrict__ bias, void* __restrict__ C,
  int M, int N, int K)
{
  __shared__ unsigned short As[128*32];
  __shared__ unsigned short Bs[128*32];
  int nbx = N >> 7;
  int bx = blockIdx.x % nbx;
  int by = blockIdx.x / nbx;
  int tid  = threadIdx.x;
  int lane = tid & 63;
  int wid  = tid >> 6;
  int wr = wid >> 1, wc = wid & 1;
  const int brow = by*128, bcol = bx*128;

  int g_r = lane >> 2;
  int g_k = (lane & 3) * 8;
  const unsigned short* Ag0 = A  + (size_t)(brow + wid*32 + g_r)*K + g_k;
  const unsigned short* Ag1 = Ag0 + (size_t)16*K;
  const unsigned short* Bg0 = Bt + (size_t)(bcol + wid*32 + g_r)*K + g_k;
  const unsigned short* Bg1 = Bg0 + (size_t)16*K;
  unsigned short* lA0 = &As[(wid*32 +  0)*32];
  unsigned short* lA1 = &As[(wid*32 + 16)*32];
  unsigned short* lB0 = &Bs[(wid*32 +  0)*32];
  unsigned short* lB1 = &Bs[(wid*32 + 16)*32];

  f32x4 acc[4][4];
  #pragma unroll
  for (int i=0;i<4;i++)
    #pragma unroll
    for (int j=0;j<4;j++) acc[i][j] = (f32x4){0.f,0.f,0.f,0.f};

  int fr = lane & 15;
  int fk = (lane >> 4) * 8;

  for (int kt = 0; kt < K; kt += 32){
    GL16(Ag0 + kt, lA0);
    GL16(Ag1 + kt, lA1);
    GL16(Bg0 + kt, lB0);
    GL16(Bg1 + kt, lB1);
    __syncthreads();
    bf16x8 af[4], bfr[4];
    #pragma unroll
    for (int i=0;i<4;i++){
      af[i]  = *(const bf16x8*)&As[(wr*64 + i*16 + fr)*32 + fk];
      bfr[i] = *(const bf16x8*)&Bs[(wc*64 + i*16 + fr)*32 + fk];
    }
    #pragma unroll
    for (int mi=0;mi<4;mi++)
      #pragma unroll
      for (int ni=0;ni<4;ni++)
        acc[mi][ni] = __builtin_amdgcn_mfma_f32_16x16x32_bf16(af[mi], bfr[ni], acc[mi][ni], 0, 0, 0);
    __syncthreads();
  }

  int col0 = bcol + wc*64 + (lane & 15);
  int row0 = brow + wr*64 + (lane >> 4)*4;
  #pragma unroll
  for (int mi=0;mi<4;mi++){
    #pragma unroll
    for (int j=0;j<4;j++){
      int r = row0 + mi*16 + j;
      #pragma unroll
      for (int ni=0;ni<4;ni++){
        int c = col0 + ni*16;
        float x = acc[mi][ni][j] + bias[c];
        if (SILU) x = x / (1.0f + expf(-x));
        if (OUT_BF16) ((unsigned short*)C)[(size_t)r*N + c] = f2bf(x);
        else          ((float*)C)[(size_t)r*N + c] = x;
      }
    }
  }
}

// ---------------------------------------------------------------------------
// Parallel merge metadata: one block of 512 threads per batch (thread = position).
__global__ __launch_bounds__(512) void merge_meta_kernel(
  const void* __restrict__ maskp, const int* __restrict__ gid,
  const int* __restrict__ flag,
  int* __restrict__ src, int* __restrict__ count)
{
  int b = blockIdx.x;
  int i = threadIdx.x;
  int lane = i & 63, w = i >> 6;
  __shared__ int sg[Ll_];
  __shared__ int fv[8];
  __shared__ int wt[8];
  int f = *flag;
  int mv;
  if (f==0)      mv = ((const int*)maskp)[b*Ll_+i];
  else if (f==1) mv = ((const unsigned char*)maskp)[b*Ll_+i];
  else           mv = (((const float*)maskp)[b*Ll_+i] != 0.0f);
  bool m = (mv != 0);
  int g = gid[b*Ll_+i];
  sg[i] = g;
  unsigned long long W = __ballot(m);
  if (lane==0) fv[w] = W ? (w*64 + __builtin_ctzll(W)) : -1;
  __syncthreads();
  unsigned long long rem = (lane==63) ? 0ull : (W >> (lane+1));
  int nxtpos = -1;
  if (rem) nxtpos = w*64 + lane + 1 + __builtin_ctzll(rem);
  else {
    #pragma unroll
    for (int k=0;k<8;k++)
      if (nxtpos < 0 && k > w && fv[k] >= 0) nxtpos = fv[k];
  }
  int nxt = (nxtpos >= 0) ? sg[nxtpos] : -1;
  bool sep = m && (nxt >= 0) && (nxt != g);
  int ci = (m?1:0) + (sep?1:0);
  int v = ci;
  #pragma unroll
  for (int off=1; off<64; off<<=1){
    int u = __shfl_up(v, off);
    if (lane >= off) v += u;
  }
  if (lane==63) wt[w] = v;
  __syncthreads();
  int woff = 0;
  #pragma unroll
  for (int k=0;k<8;k++) if (k < w) woff += wt[k];
  int e = woff + v - ci;
  int* sb = src + b*Mm_;
  if (m){
    sb[e] = 2*i;
    if (sep) sb[e+1] = 2*i+1;
  }
  if (i==0){
    int tot=0;
    #pragma unroll
    for (int k=0;k<8;k++) tot += wt[k];
    count[b] = tot;
  }
}

// ---------------------------------------------------------------------------
// Final output: right-aligned pieces + pos_emb, zeros elsewhere, plus mask plane.
__global__ __launch_bounds__(256) void output_kernel(
  const float* __restrict__ ev, const float* __restrict__ pos_emb,
  const float* __restrict__ sep_token,
  const int* __restrict__ src, const int* __restrict__ count,
  float* __restrict__ out)
{
  int tid  = threadIdx.x;
  int tpos = blockIdx.x*4 + (tid>>6);
  int lane = tid & 63;
  int b = tpos >> 10;
  int t = tpos & 1023;
  int cnt = count[b];
  int start = Mm_ - cnt;
  float4 val = make_float4(0.f,0.f,0.f,0.f);
  float maskv = 0.f;
  if (t >= start){
    maskv = 1.f;
    int slot = src[b*Mm_ + (t - start)];
    const float* sv = (slot & 1) ? sep_token
                                 : ev + (size_t)(b*Ll_ + (slot>>1))*Hh;
    float4 x = *(const float4*)(sv + lane*4);
    float4 p = *(const float4*)(pos_emb + (size_t)t*Hh + lane*4);
    val = make_float4(x.x+p.x, x.y+p.y, x.z+p.z, x.w+p.w);
  }
  *(float4*)(out + (size_t)tpos*Hh + lane*4) = val;
  if (lane==0) out[(size_t)Bb_*Mm_*Hh + tpos] = maskv;
}

// ---------------------------------------------------------------------------
extern "C" void kernel_launch(void* const* d_in, const int* in_sizes, int n_in,
                              void* d_out, int out_size, void* d_ws, size_t ws_size,
                              hipStream_t stream) {
  const int* tok    = (const int*)d_in[0];
  const int* post   = (const int*)d_in[1];
  const int* auth   = (const int*)d_in[2];
  const int* act    = (const int*)d_in[3];
  const int* tg     = (const int*)d_in[4];
  const int* gid    = (const int*)d_in[5];
  const void* maskp =             d_in[6];
  const float* token_emb = (const float*)d_in[7];
  const float* time_emb  = (const float*)d_in[8];
  const float* group_emb = (const float*)d_in[9];
  const float* pos_emb   = (const float*)d_in[10];
  const float* sep_token = (const float*)d_in[11];
  const float* ln_g = (const float*)d_in[12];
  const float* ln_b = (const float*)d_in[13];
  const float* W1   = (const float*)d_in[14];
  const float* b1   = (const float*)d_in[15];
  const float* W2   = (const float*)d_in[16];
  const float* b2   = (const float*)d_in[17];

  char* ws = (char*)d_ws;
  size_t off = 0;
  int* flag = (int*)ws;                                  off += 256;
  unsigned short* xn  = (unsigned short*)(ws + off);     off += (size_t)BL_*SIXH*2;
  unsigned short* h1  = (unsigned short*)(ws + off);     off += (size_t)BL_*N1_*2;
  float*          ev  = (float*)(ws + off);              off += (size_t)BL_*N2_*4;
  unsigned short* w1t = (unsigned short*)(ws + off);     off += (size_t)K1_*N1_*2;
  unsigned short* w2t = (unsigned short*)(ws + off);     off += (size_t)K2_*N2_*2;
  int*            src = (int*)(ws + off);                off += (size_t)Bb_*Mm_*4;
  int*            cnt = (int*)(ws + off);                off += 256;

  detect_mask_kernel<<<1,256,0,stream>>>((const unsigned int*)maskp, flag);
  transpose_conv_kernel<<<(K1_/32)*(N1_/32),256,0,stream>>>(W1, w1t, K1_, N1_);
  transpose_conv_kernel<<<(K2_/32)*(N2_/32),256,0,stream>>>(W2, w2t, K2_, N2_);
  gather_ln_kernel<<<BL_,256,0,stream>>>(tok,post,auth,act,tg,gid,
                                         token_emb,time_emb,group_emb,
                                         ln_g,ln_b,xn);
  gemm1_m201_kernel<<<(BL_/256)*(N1_/256),512,0,stream>>>(
      xn, w1t, b1, h1, BL_, N1_, K1_);
  gemm_mfma_kernel<false,false><<<(BL_/128)*(N2_/128),256,0,stream>>>(
      h1, w2t, b2, (void*)ev, BL_, N2_, K2_);
  merge_meta_kernel<<<Bb_,512,0,stream>>>(maskp, gid, flag, src, cnt);
  output_kernel<<<(Bb_*Mm_)/4,256,0,stream>>>(ev, pos_emb, sep_token, src, cnt, (float*)d_out);
}